// Round 4
// baseline (700.048 us; speedup 1.0000x reference)
//
#include <hip/hip_runtime.h>

typedef unsigned short u16;
typedef __bf16 bf16x8 __attribute__((ext_vector_type(8)));
typedef float f32x4 __attribute__((ext_vector_type(4)));

#define B_ 32
#define T_ 512
#define H_ 1024
#define E_ 2048
#define S_ 128

__device__ inline u16 f2bf(float f) {
  union { float f; unsigned int u; } c; c.f = f;
  unsigned int u = c.u;
  unsigned int r = (u + 0x7FFFu + ((u >> 16) & 1u)) >> 16;
  return (u16)r;
}
__device__ inline float bf2f(u16 h) {
  union { unsigned int u; float f; } c; c.u = ((unsigned int)h) << 16; return c.f;
}

// async 16B global->LDS DMA (m97: width=16 => global_load_lds_dwordx4)
__device__ inline void g2lds16(const u16* g, u16* l) {
  __builtin_amdgcn_global_load_lds(
      (const __attribute__((address_space(1))) void*)g,
      (__attribute__((address_space(3))) void*)l, 16, 0, 0);
}

// ---------------- LayerNorm: one block (256 thr) per row of H=1024 -----------
__global__ __launch_bounds__(256) void ln_kernel(const float* __restrict__ x,
                                                 const float* __restrict__ lw,
                                                 const float* __restrict__ lb,
                                                 u16* __restrict__ xn) {
  int row = blockIdx.x;
  int t = threadIdx.x;
  const float4* xr = (const float4*)(x + (size_t)row * H_);
  float4 v = xr[t];
  float s = v.x + v.y + v.z + v.w;
  float ss = v.x * v.x + v.y * v.y + v.z * v.z + v.w * v.w;
  for (int off = 1; off < 64; off <<= 1) {
    s += __shfl_xor(s, off);
    ss += __shfl_xor(ss, off);
  }
  __shared__ float red[8];
  int w = t >> 6, l = t & 63;
  if (l == 0) { red[w] = s; red[4 + w] = ss; }
  __syncthreads();
  s = red[0] + red[1] + red[2] + red[3];
  ss = red[4] + red[5] + red[6] + red[7];
  float mu = s * (1.0f / H_);
  float var = ss * (1.0f / H_) - mu * mu;
  float inv = rsqrtf(var + 1e-5f);
  int i = t * 4;
  ushort4 o;
  o.x = f2bf((v.x - mu) * inv * lw[i] + lb[i]);
  o.y = f2bf((v.y - mu) * inv * lw[i + 1] + lb[i + 1]);
  o.z = f2bf((v.z - mu) * inv * lw[i + 2] + lb[i + 2]);
  o.w = f2bf((v.w - mu) * inv * lw[i + 3] + lb[i + 3]);
  *(ushort4*)(xn + (size_t)row * H_ + i) = o;
}

// ---------------- f32 -> bf16 converter (n4 = count/4) -----------------------
__global__ void cvt_kernel(const float* __restrict__ in, u16* __restrict__ out, int n4) {
  int i = blockIdx.x * 256 + threadIdx.x;
  if (i < n4) {
    float4 v = ((const float4*)in)[i];
    ushort4 o;
    o.x = f2bf(v.x); o.y = f2bf(v.y); o.z = f2bf(v.z); o.w = f2bf(v.w);
    ((ushort4*)out)[i] = o;
  }
}

// ---------------- gamma/beta + RoPE -> q,k (bf16) ----------------------------
__global__ __launch_bounds__(256) void rope_kernel(const float* __restrict__ base,
                                                   const float* __restrict__ gamma,
                                                   const float* __restrict__ beta,
                                                   u16* __restrict__ q,
                                                   u16* __restrict__ k) {
  int row = blockIdx.x * 4 + (threadIdx.x >> 6);  // b*T + t
  int s = threadIdx.x & 63;
  int t = row & (T_ - 1);
  const float* bp = base + (size_t)row * S_;
  float b1 = bp[s], b2 = bp[s + 64];
  float q1 = b1 * gamma[s] + beta[s];
  float q2 = b2 * gamma[64 + s] + beta[64 + s];
  float k1 = b1 * gamma[128 + s] + beta[128 + s];
  float k2 = b2 * gamma[192 + s] + beta[192 + s];
  float invf = (float)pow(10000.0, (double)s * (1.0 / 64.0));
  float ph = (float)t * invf;
  float sn, cs;
  sincosf(ph, &sn, &cs);
  size_t o = (size_t)row * S_;
  q[o + s]      = f2bf(q1 * cs - q2 * sn);
  q[o + 64 + s] = f2bf(q2 * cs + q1 * sn);
  k[o + s]      = f2bf(k1 * cs - k2 * sn);
  k[o + 64 + s] = f2bf(k2 * cs + k1 * sn);
}

// ---------------- 128x128-tile bf16 MFMA GEMM, B^T form ----------------------
// C[m][n] = sum_k A[m][k] * B[n][k];  A: M x K row-major, B: N x K row-major.
// grid: (N/128, M/128, Z). MODE selects fused epilogue.
// Staging: global_load_lds width=16 (m97 structure). LDS layout is
// lane-contiguous: thread t's 16B chunk lands at byte offset t*16 within
// each 4KB half -> wave-uniform base + lane*16, the DMA's requirement.
template <int MODE>
__global__ __launch_bounds__(256)
void gemm_bt(const u16* __restrict__ A, const u16* __restrict__ Bm,
             int K, long long sA, long long sB,
             void* __restrict__ o0, void* __restrict__ o1, void* __restrict__ o2,
             const void* __restrict__ c0, const void* __restrict__ c1) {
  // 16 KB LDS: staging buffers for the k-loop; reused as transpose buffer
  // in the MODE=0 v-path epilogue (two 64x128 halves).
  __shared__ __attribute__((aligned(16))) u16 lds[8192];
  u16* lsA = lds;          // 128 rows x 32 cols
  u16* lsB = lds + 4096;   // 128 rows x 32 cols

  const int z = blockIdx.z;
  const u16* Ab = A + (long long)z * sA;
  const u16* Bb = Bm + (long long)z * sB;
  const int m0 = blockIdx.y * 128;
  const int n0 = blockIdx.x * 128;
  const int t = threadIdx.x;
  const int w = t >> 6, l = t & 63;
  const int quad = l >> 4, l16 = l & 15;
  const int wm = (w >> 1) * 64, wn = (w & 1) * 64;
  const int sr = t >> 2;          // staging row 0..63
  const int sc = (t & 3) * 8;     // staging col {0,8,16,24}

  f32x4 zero = {0.f, 0.f, 0.f, 0.f};
  f32x4 acc[4][4];
  for (int mi = 0; mi < 4; ++mi)
    for (int ni = 0; ni < 4; ++ni) acc[mi][ni] = zero;

  const u16* gA0 = Ab + ((size_t)(m0 + sr) * K + sc);
  const u16* gA1 = Ab + ((size_t)(m0 + 64 + sr) * K + sc);
  const u16* gB0 = Bb + ((size_t)(n0 + sr) * K + sc);
  const u16* gB1 = Bb + ((size_t)(n0 + 64 + sr) * K + sc);
  u16* dA0 = &lsA[sr * 32 + sc];
  u16* dA1 = &lsA[(64 + sr) * 32 + sc];
  u16* dB0 = &lsB[sr * 32 + sc];
  u16* dB1 = &lsB[(64 + sr) * 32 + sc];

  for (int k0 = 0; k0 < K; k0 += 32) {
    __syncthreads();  // previous iteration's LDS reads complete
    g2lds16(gA0 + k0, dA0);
    g2lds16(gA1 + k0, dA1);
    g2lds16(gB0 + k0, dB0);
    g2lds16(gB1 + k0, dB1);
    __syncthreads();  // compiler drains vmcnt(0) before s_barrier
    bf16x8 af[4], bfr[4];
    for (int i = 0; i < 4; ++i) {
      af[i]  = *(const bf16x8*)&lsA[(wm + i * 16 + l16) * 32 + quad * 8];
      bfr[i] = *(const bf16x8*)&lsB[(wn + i * 16 + l16) * 32 + quad * 8];
    }
    for (int mi = 0; mi < 4; ++mi)
      for (int ni = 0; ni < 4; ++ni)
        acc[mi][ni] = __builtin_amdgcn_mfma_f32_16x16x32_bf16(af[mi], bfr[ni], acc[mi][ni], 0, 0, 0);
  }

  // epilogue: C/D layout col = lane&15, row = quad*4 + reg   (m89/m91 verified)
  if constexpr (MODE == 0) {
    const float* uvb = (const float*)c0;
    if (n0 < E_) {
      // ---- u path: coalesced bf16 store, row-major m*E + n
      for (int mi = 0; mi < 4; ++mi)
        for (int ni = 0; ni < 4; ++ni) {
          int n = n0 + wn + ni * 16 + l16;
          float bias = uvb[n];
          for (int r = 0; r < 4; ++r) {
            int m = m0 + wm + mi * 16 + quad * 4 + r;
            float vb = acc[mi][ni][r] + bias;
            ((u16*)o0)[(size_t)m * E_ + n] = f2bf(vb / (1.0f + expf(-vb)));
          }
        }
    } else if (n0 < 2 * E_) {
      // ---- v path: transpose through LDS, then coalesced rows of vt
      const int bb = m0 >> 9;          // batch
      const int tt0 = m0 & (T_ - 1);   // t offset within batch
      const int nv0 = n0 - E_;
      for (int h = 0; h < 2; ++h) {
        __syncthreads();               // LDS free (k-loop reads / prev half done)
        if ((w & 1) == h) {            // waves holding n in [n0+h*64, n0+h*64+64)
          for (int mi = 0; mi < 4; ++mi)
            for (int ni = 0; ni < 4; ++ni) {
              int nl = ni * 16 + l16;                 // 0..63 within half
              float bias = uvb[n0 + h * 64 + nl];
              for (int r = 0; r < 4; ++r) {
                int ml = wm + mi * 16 + quad * 4 + r; // 0..127
                float vb = acc[mi][ni][r] + bias;
                u16 sv = f2bf(vb / (1.0f + expf(-vb)));
                int g = ml >> 3, o = ml & 7;
                int gs = g ^ (nl & 7);                // XOR swizzle, 8-elem granule
                lds[nl * 128 + gs * 8 + o] = sv;
              }
            }
        }
        __syncthreads();
        // readback: 256 threads; row = t>>2 (0..63), 4 x 16B chunks per thread
        int row = t >> 2;
        int q4 = t & 3;
        size_t gbase = ((size_t)bb * E_ + nv0 + h * 64 + row) * T_ + tt0;
        for (int gg = 0; gg < 4; ++gg) {
          int g = q4 * 4 + gg;
          int gsw = g ^ (row & 7);
          uint4 val = *(const uint4*)&lds[row * 128 + gsw * 8];
          *(uint4*)&(((u16*)o1)[gbase + g * 8]) = val;
        }
      }
    } else {
      // ---- base path: f32 store, m*S + n', coalesced 64B chunks
      for (int mi = 0; mi < 4; ++mi)
        for (int ni = 0; ni < 4; ++ni) {
          int n = n0 + wn + ni * 16 + l16;
          float bias = uvb[n];
          for (int r = 0; r < 4; ++r) {
            int m = m0 + wm + mi * 16 + quad * 4 + r;
            float vb = acc[mi][ni][r] + bias;
            ((float*)o2)[(size_t)m * S_ + (n - 2 * E_)] = vb / (1.0f + expf(-vb));
          }
        }
    }
  } else {
    for (int mi = 0; mi < 4; ++mi) {
      for (int ni = 0; ni < 4; ++ni) {
        int n = n0 + wn + ni * 16 + l16;
        for (int r = 0; r < 4; ++r) {
          int m = m0 + wm + mi * 16 + quad * 4 + r;
          float a = acc[mi][ni][r];
          if constexpr (MODE == 1) {
            // kernel = relu(qk/sqrt(S) + w[n-m+511])^2  -> bf16
            const float* wrel = (const float*)c0;
            float v = a * 0.08838834764831845f + wrel[n - m + 511];
            v = fmaxf(v, 0.0f);
            ((u16*)o0)[(size_t)z * (T_ * T_) + (size_t)m * T_ + n] = f2bf(v * v);
          } else if constexpr (MODE == 2) {
            // attn = (kernel @ v) * u  -> bf16, IN PLACE over u (o0 == c0)
            const u16* uu = (const u16*)c0;
            size_t gi = ((size_t)z * T_ + m) * E_ + n;
            float uv_ = bf2f(uu[gi]);  // read before write, same thread, same index
            ((u16*)o0)[gi] = f2bf(a * uv_);
          } else {
            // out = acc + o_b + shortcut  -> f32
            const float* ob = (const float*)c0;
            const float* xs = (const float*)c1;
            size_t gi = (size_t)m * H_ + n;
            ((float*)o0)[gi] = a + ob[n] + xs[gi];
          }
        }
      }
    }
  }
}

extern "C" void kernel_launch(void* const* d_in, const int* in_sizes, int n_in,
                              void* d_out, int out_size, void* d_ws, size_t ws_size,
                              hipStream_t stream) {
  const float* x     = (const float*)d_in[0];
  const float* ln_w  = (const float*)d_in[1];
  const float* ln_b  = (const float*)d_in[2];
  const float* uv_w  = (const float*)d_in[3];
  const float* uv_b  = (const float*)d_in[4];
  const float* gamma = (const float*)d_in[5];
  const float* beta  = (const float*)d_in[6];
  const float* wrel  = (const float*)d_in[7];
  const float* o_w   = (const float*)d_in[8];
  const float* o_b   = (const float*)d_in[9];

  // Workspace layout (total 189,005,824 B ≈ 180.3 MiB), with aliasing:
  //  - qb/kb/km live in the xn region (xn dead after GEMM0; stream-ordered)
  //  - attn is written in-place over u (element-wise read-then-write)
  char* ws = (char*)d_ws;
  u16*   xn   = (u16*)(ws);                 // 16384x1024 bf16  = 33554432 B
  u16*   qb   = (u16*)(ws);                 // 32x512x128 bf16  =  4194304 B (aliases xn)
  u16*   kb   = (u16*)(ws + 4194304);       // 32x512x128 bf16  =  4194304 B (aliases xn)
  u16*   km   = (u16*)(ws + 8388608);       // 32x512x512 bf16  = 16777216 B (aliases xn)
  u16*   uvwb = (u16*)(ws + 33554432);      // 4224x1024 bf16   =  8650752 B
  u16*   owb  = (u16*)(ws + 42205184);      // 1024x2048 bf16   =  4194304 B
  u16*   u    = (u16*)(ws + 46399488);      // 16384x2048 bf16  = 67108864 B (attn in-place)
  u16*   vt   = (u16*)(ws + 113508352);     // 32x2048x512 bf16 = 67108864 B
  float* base = (float*)(ws + 180617216);   // 16384x128 f32    =  8388608 B
  u16*   attn = u;

  // 1. LayerNorm -> bf16
  ln_kernel<<<16384, 256, 0, stream>>>(x, ln_w, ln_b, xn);
  // 2. weight conversions
  cvt_kernel<<<4224, 256, 0, stream>>>(uv_w, uvwb, 4224 * 1024 / 4);
  cvt_kernel<<<2048, 256, 0, stream>>>(o_w, owb, 1024 * 2048 / 4);
  // 3. uv GEMM: M=16384, N=4224, K=1024; epilogue silu + split u / v^T / base
  gemm_bt<0><<<dim3(33, 128, 1), 256, 0, stream>>>(xn, uvwb, 1024, 0, 0,
                                                   u, vt, base, uv_b, nullptr);
  // 4. gamma/beta + RoPE -> q,k  (xn now dead; qb/kb alias it)
  rope_kernel<<<4096, 256, 0, stream>>>(base, gamma, beta, qb, kb);
  // 5. qk per batch: M=N=512, K=128; epilogue bias + relu^2
  gemm_bt<1><<<dim3(4, 4, 32), 256, 0, stream>>>(qb, kb, 128, 65536, 65536,
                                                 km, nullptr, nullptr, wrel, nullptr);
  // 6. kernel @ v per batch: M=512, N=2048, K=512; epilogue * u (in place)
  gemm_bt<2><<<dim3(16, 4, 32), 256, 0, stream>>>(km, vt, 512, 262144, 1048576,
                                                  attn, nullptr, nullptr, u, nullptr);
  // 7. final: M=16384, N=1024, K=2048; epilogue + o_b + shortcut
  gemm_bt<3><<<dim3(8, 128, 1), 256, 0, stream>>>(attn, owb, 2048, 0, 0,
                                                  d_out, nullptr, nullptr, o_b, x);
}

// Round 5
// 696.192 us; speedup vs baseline: 1.0055x; 1.0055x over previous
//
#include <hip/hip_runtime.h>

typedef unsigned short u16;
typedef __bf16 bf16x8 __attribute__((ext_vector_type(8)));
typedef float f32x4 __attribute__((ext_vector_type(4)));

#define B_ 32
#define T_ 512
#define H_ 1024
#define E_ 2048
#define S_ 128

__device__ inline u16 f2bf(float f) {
  union { float f; unsigned int u; } c; c.f = f;
  unsigned int u = c.u;
  unsigned int r = (u + 0x7FFFu + ((u >> 16) & 1u)) >> 16;
  return (u16)r;
}
__device__ inline float bf2f(u16 h) {
  union { unsigned int u; float f; } c; c.u = ((unsigned int)h) << 16; return c.f;
}

// async 16B global->LDS DMA (m97: width=16 => global_load_lds_dwordx4)
__device__ inline void g2lds16(const u16* g, u16* l) {
  __builtin_amdgcn_global_load_lds(
      (const __attribute__((address_space(1))) void*)g,
      (__attribute__((address_space(3))) void*)l, 16, 0, 0);
}

// ---------------- LayerNorm: one block (256 thr) per row of H=1024 -----------
__global__ __launch_bounds__(256) void ln_kernel(const float* __restrict__ x,
                                                 const float* __restrict__ lw,
                                                 const float* __restrict__ lb,
                                                 u16* __restrict__ xn) {
  int row = blockIdx.x;
  int t = threadIdx.x;
  const float4* xr = (const float4*)(x + (size_t)row * H_);
  float4 v = xr[t];
  float s = v.x + v.y + v.z + v.w;
  float ss = v.x * v.x + v.y * v.y + v.z * v.z + v.w * v.w;
  for (int off = 1; off < 64; off <<= 1) {
    s += __shfl_xor(s, off);
    ss += __shfl_xor(ss, off);
  }
  __shared__ float red[8];
  int w = t >> 6, l = t & 63;
  if (l == 0) { red[w] = s; red[4 + w] = ss; }
  __syncthreads();
  s = red[0] + red[1] + red[2] + red[3];
  ss = red[4] + red[5] + red[6] + red[7];
  float mu = s * (1.0f / H_);
  float var = ss * (1.0f / H_) - mu * mu;
  float inv = rsqrtf(var + 1e-5f);
  int i = t * 4;
  ushort4 o;
  o.x = f2bf((v.x - mu) * inv * lw[i] + lb[i]);
  o.y = f2bf((v.y - mu) * inv * lw[i + 1] + lb[i + 1]);
  o.z = f2bf((v.z - mu) * inv * lw[i + 2] + lb[i + 2]);
  o.w = f2bf((v.w - mu) * inv * lw[i + 3] + lb[i + 3]);
  *(ushort4*)(xn + (size_t)row * H_ + i) = o;
}

// ---------------- f32 -> bf16 converter (n4 = count/4) -----------------------
__global__ void cvt_kernel(const float* __restrict__ in, u16* __restrict__ out, int n4) {
  int i = blockIdx.x * 256 + threadIdx.x;
  if (i < n4) {
    float4 v = ((const float4*)in)[i];
    ushort4 o;
    o.x = f2bf(v.x); o.y = f2bf(v.y); o.z = f2bf(v.z); o.w = f2bf(v.w);
    ((ushort4*)out)[i] = o;
  }
}

// ---------------- gamma/beta + RoPE -> q,k (bf16) ----------------------------
__global__ __launch_bounds__(256) void rope_kernel(const float* __restrict__ base,
                                                   const float* __restrict__ gamma,
                                                   const float* __restrict__ beta,
                                                   u16* __restrict__ q,
                                                   u16* __restrict__ k) {
  int row = blockIdx.x * 4 + (threadIdx.x >> 6);  // b*T + t
  int s = threadIdx.x & 63;
  int t = row & (T_ - 1);
  const float* bp = base + (size_t)row * S_;
  float b1 = bp[s], b2 = bp[s + 64];
  float q1 = b1 * gamma[s] + beta[s];
  float q2 = b2 * gamma[64 + s] + beta[64 + s];
  float k1 = b1 * gamma[128 + s] + beta[128 + s];
  float k2 = b2 * gamma[192 + s] + beta[192 + s];
  float invf = (float)pow(10000.0, (double)s * (1.0 / 64.0));
  float ph = (float)t * invf;
  float sn, cs;
  sincosf(ph, &sn, &cs);
  size_t o = (size_t)row * S_;
  q[o + s]      = f2bf(q1 * cs - q2 * sn);
  q[o + 64 + s] = f2bf(q2 * cs + q1 * sn);
  k[o + s]      = f2bf(k1 * cs - k2 * sn);
  k[o + 64 + s] = f2bf(k2 * cs + k1 * sn);
}

// ---------------- 128x128-tile bf16 MFMA GEMM, B^T form ----------------------
// C[m][n] = sum_k A[m][k] * B[n][k];  A: M x K row-major, B: N x K row-major.
// grid: (N/128, M/128, Z). MODE selects fused epilogue.
// Staging via global_load_lds width=16. LDS destination is lane-linear (t*16
// per 4KB half) as the DMA requires; bank-conflict avoidance is done by
// PERMUTING THE GLOBAL SOURCE GRANULE instead: thread t fetches 16B granule
// (t&3)^((t>>3)&3) of its row, so physical LDS granule p of row r holds
// global granule p ^ ((r>>1)&3). Fragment reads then address granule
// quad ^ ((l16>>1)&3): every 8 consecutive lanes of a ds_read_b128 cover all
// 32 banks exactly once (was: 4 lanes on the same 4-bank group).
template <int MODE>
__global__ __launch_bounds__(256)
void gemm_bt(const u16* __restrict__ A, const u16* __restrict__ Bm,
             int K, long long sA, long long sB,
             void* __restrict__ o0, void* __restrict__ o1, void* __restrict__ o2,
             const void* __restrict__ c0, const void* __restrict__ c1) {
  // 16 KB LDS: staging buffers for the k-loop; reused as transpose buffer
  // in the MODE=0 v-path epilogue (two 64x128 halves).
  __shared__ __attribute__((aligned(16))) u16 lds[8192];
  u16* lsA = lds;          // 128 rows x 32 cols
  u16* lsB = lds + 4096;   // 128 rows x 32 cols

  const int z = blockIdx.z;
  const u16* Ab = A + (long long)z * sA;
  const u16* Bb = Bm + (long long)z * sB;
  const int m0 = blockIdx.y * 128;
  const int n0 = blockIdx.x * 128;
  const int t = threadIdx.x;
  const int w = t >> 6, l = t & 63;
  const int quad = l >> 4, l16 = l & 15;
  const int wm = (w >> 1) * 64, wn = (w & 1) * 64;
  const int sr = t >> 2;                    // staging row 0..63
  const int gl = (t & 3) ^ ((t >> 3) & 3);  // swizzled SOURCE granule
  const int sc = gl * 8;                    // source col (elements)
  const int dc = (t & 3) * 8;               // dest col: lane-linear (DMA req.)
  const int pswz = quad ^ ((l16 >> 1) & 3); // physical granule for frag reads

  f32x4 zero = {0.f, 0.f, 0.f, 0.f};
  f32x4 acc[4][4];
  for (int mi = 0; mi < 4; ++mi)
    for (int ni = 0; ni < 4; ++ni) acc[mi][ni] = zero;

  const u16* gA0 = Ab + ((size_t)(m0 + sr) * K + sc);
  const u16* gA1 = Ab + ((size_t)(m0 + 64 + sr) * K + sc);
  const u16* gB0 = Bb + ((size_t)(n0 + sr) * K + sc);
  const u16* gB1 = Bb + ((size_t)(n0 + 64 + sr) * K + sc);
  u16* dA0 = &lsA[sr * 32 + dc];
  u16* dA1 = &lsA[(64 + sr) * 32 + dc];
  u16* dB0 = &lsB[sr * 32 + dc];
  u16* dB1 = &lsB[(64 + sr) * 32 + dc];

  for (int k0 = 0; k0 < K; k0 += 32) {
    __syncthreads();  // previous iteration's LDS reads complete
    g2lds16(gA0 + k0, dA0);
    g2lds16(gA1 + k0, dA1);
    g2lds16(gB0 + k0, dB0);
    g2lds16(gB1 + k0, dB1);
    __syncthreads();  // compiler drains vmcnt(0) before s_barrier
    bf16x8 af[4], bfr[4];
    for (int i = 0; i < 4; ++i) {
      af[i]  = *(const bf16x8*)&lsA[(wm + i * 16 + l16) * 32 + pswz * 8];
      bfr[i] = *(const bf16x8*)&lsB[(wn + i * 16 + l16) * 32 + pswz * 8];
    }
    for (int mi = 0; mi < 4; ++mi)
      for (int ni = 0; ni < 4; ++ni)
        acc[mi][ni] = __builtin_amdgcn_mfma_f32_16x16x32_bf16(af[mi], bfr[ni], acc[mi][ni], 0, 0, 0);
  }

  // epilogue: C/D layout col = lane&15, row = quad*4 + reg   (m89/m91 verified)
  if constexpr (MODE == 0) {
    const float* uvb = (const float*)c0;
    if (n0 < E_) {
      // ---- u path: coalesced bf16 store, row-major m*E + n
      for (int mi = 0; mi < 4; ++mi)
        for (int ni = 0; ni < 4; ++ni) {
          int n = n0 + wn + ni * 16 + l16;
          float bias = uvb[n];
          for (int r = 0; r < 4; ++r) {
            int m = m0 + wm + mi * 16 + quad * 4 + r;
            float vb = acc[mi][ni][r] + bias;
            ((u16*)o0)[(size_t)m * E_ + n] = f2bf(vb / (1.0f + expf(-vb)));
          }
        }
    } else if (n0 < 2 * E_) {
      // ---- v path: transpose through LDS, then coalesced rows of vt
      const int bb = m0 >> 9;          // batch
      const int tt0 = m0 & (T_ - 1);   // t offset within batch
      const int nv0 = n0 - E_;
      for (int h = 0; h < 2; ++h) {
        __syncthreads();               // LDS free (k-loop reads / prev half done)
        if ((w & 1) == h) {            // waves holding n in [n0+h*64, n0+h*64+64)
          for (int mi = 0; mi < 4; ++mi)
            for (int ni = 0; ni < 4; ++ni) {
              int nl = ni * 16 + l16;                 // 0..63 within half
              float bias = uvb[n0 + h * 64 + nl];
              for (int r = 0; r < 4; ++r) {
                int ml = wm + mi * 16 + quad * 4 + r; // 0..127
                float vb = acc[mi][ni][r] + bias;
                u16 sv = f2bf(vb / (1.0f + expf(-vb)));
                int g = ml >> 3, o = ml & 7;
                int gs = g ^ (nl & 7);                // XOR swizzle, 8-elem granule
                lds[nl * 128 + gs * 8 + o] = sv;
              }
            }
        }
        __syncthreads();
        // readback: 256 threads; row = t>>2 (0..63), 4 x 16B chunks per thread
        int row = t >> 2;
        int q4 = t & 3;
        size_t gbase = ((size_t)bb * E_ + nv0 + h * 64 + row) * T_ + tt0;
        for (int gg = 0; gg < 4; ++gg) {
          int g = q4 * 4 + gg;
          int gsw = g ^ (row & 7);
          uint4 val = *(const uint4*)&lds[row * 128 + gsw * 8];
          *(uint4*)&(((u16*)o1)[gbase + g * 8]) = val;
        }
      }
    } else {
      // ---- base path: f32 store, m*S + n', coalesced 64B chunks
      for (int mi = 0; mi < 4; ++mi)
        for (int ni = 0; ni < 4; ++ni) {
          int n = n0 + wn + ni * 16 + l16;
          float bias = uvb[n];
          for (int r = 0; r < 4; ++r) {
            int m = m0 + wm + mi * 16 + quad * 4 + r;
            float vb = acc[mi][ni][r] + bias;
            ((float*)o2)[(size_t)m * S_ + (n - 2 * E_)] = vb / (1.0f + expf(-vb));
          }
        }
    }
  } else {
    for (int mi = 0; mi < 4; ++mi) {
      for (int ni = 0; ni < 4; ++ni) {
        int n = n0 + wn + ni * 16 + l16;
        for (int r = 0; r < 4; ++r) {
          int m = m0 + wm + mi * 16 + quad * 4 + r;
          float a = acc[mi][ni][r];
          if constexpr (MODE == 1) {
            // kernel = relu(qk/sqrt(S) + w[n-m+511])^2  -> bf16
            const float* wrel = (const float*)c0;
            float v = a * 0.08838834764831845f + wrel[n - m + 511];
            v = fmaxf(v, 0.0f);
            ((u16*)o0)[(size_t)z * (T_ * T_) + (size_t)m * T_ + n] = f2bf(v * v);
          } else if constexpr (MODE == 2) {
            // attn = (kernel @ v) * u  -> bf16, IN PLACE over u (o0 == c0)
            const u16* uu = (const u16*)c0;
            size_t gi = ((size_t)z * T_ + m) * E_ + n;
            float uv_ = bf2f(uu[gi]);  // read before write, same thread, same index
            ((u16*)o0)[gi] = f2bf(a * uv_);
          } else {
            // out = acc + o_b + shortcut  -> f32
            const float* ob = (const float*)c0;
            const float* xs = (const float*)c1;
            size_t gi = (size_t)m * H_ + n;
            ((float*)o0)[gi] = a + ob[n] + xs[gi];
          }
        }
      }
    }
  }
}

extern "C" void kernel_launch(void* const* d_in, const int* in_sizes, int n_in,
                              void* d_out, int out_size, void* d_ws, size_t ws_size,
                              hipStream_t stream) {
  const float* x     = (const float*)d_in[0];
  const float* ln_w  = (const float*)d_in[1];
  const float* ln_b  = (const float*)d_in[2];
  const float* uv_w  = (const float*)d_in[3];
  const float* uv_b  = (const float*)d_in[4];
  const float* gamma = (const float*)d_in[5];
  const float* beta  = (const float*)d_in[6];
  const float* wrel  = (const float*)d_in[7];
  const float* o_w   = (const float*)d_in[8];
  const float* o_b   = (const float*)d_in[9];

  // Workspace layout (total 189,005,824 B ≈ 180.3 MiB), with aliasing:
  //  - qb/kb/km live in the xn region (xn dead after GEMM0; stream-ordered)
  //  - attn is written in-place over u (element-wise read-then-write)
  char* ws = (char*)d_ws;
  u16*   xn   = (u16*)(ws);                 // 16384x1024 bf16  = 33554432 B
  u16*   qb   = (u16*)(ws);                 // 32x512x128 bf16  =  4194304 B (aliases xn)
  u16*   kb   = (u16*)(ws + 4194304);       // 32x512x128 bf16  =  4194304 B (aliases xn)
  u16*   km   = (u16*)(ws + 8388608);       // 32x512x512 bf16  = 16777216 B (aliases xn)
  u16*   uvwb = (u16*)(ws + 33554432);      // 4224x1024 bf16   =  8650752 B
  u16*   owb  = (u16*)(ws + 42205184);      // 1024x2048 bf16   =  4194304 B
  u16*   u    = (u16*)(ws + 46399488);      // 16384x2048 bf16  = 67108864 B (attn in-place)
  u16*   vt   = (u16*)(ws + 113508352);     // 32x2048x512 bf16 = 67108864 B
  float* base = (float*)(ws + 180617216);   // 16384x128 f32    =  8388608 B
  u16*   attn = u;

  // 1. LayerNorm -> bf16
  ln_kernel<<<16384, 256, 0, stream>>>(x, ln_w, ln_b, xn);
  // 2. weight conversions
  cvt_kernel<<<4224, 256, 0, stream>>>(uv_w, uvwb, 4224 * 1024 / 4);
  cvt_kernel<<<2048, 256, 0, stream>>>(o_w, owb, 1024 * 2048 / 4);
  // 3. uv GEMM: M=16384, N=4224, K=1024; epilogue silu + split u / v^T / base
  gemm_bt<0><<<dim3(33, 128, 1), 256, 0, stream>>>(xn, uvwb, 1024, 0, 0,
                                                   u, vt, base, uv_b, nullptr);
  // 4. gamma/beta + RoPE -> q,k  (xn now dead; qb/kb alias it)
  rope_kernel<<<4096, 256, 0, stream>>>(base, gamma, beta, qb, kb);
  // 5. qk per batch: M=N=512, K=128; epilogue bias + relu^2
  gemm_bt<1><<<dim3(4, 4, 32), 256, 0, stream>>>(qb, kb, 128, 65536, 65536,
                                                 km, nullptr, nullptr, wrel, nullptr);
  // 6. kernel @ v per batch: M=512, N=2048, K=512; epilogue * u (in place)
  gemm_bt<2><<<dim3(16, 4, 32), 256, 0, stream>>>(km, vt, 512, 262144, 1048576,
                                                  attn, nullptr, nullptr, u, nullptr);
  // 7. final: M=16384, N=1024, K=2048; epilogue + o_b + shortcut
  gemm_bt<3><<<dim3(8, 128, 1), 256, 0, stream>>>(attn, owb, 2048, 0, 0,
                                                  d_out, nullptr, nullptr, o_b, x);
}

// Round 6
// 580.278 us; speedup vs baseline: 1.2064x; 1.1998x over previous
//
#include <hip/hip_runtime.h>

typedef unsigned short u16;
typedef __bf16 bf16x8 __attribute__((ext_vector_type(8)));
typedef float f32x4 __attribute__((ext_vector_type(4)));

#define B_ 32
#define T_ 512
#define H_ 1024
#define E_ 2048
#define S_ 128

__device__ inline u16 f2bf(float f) {
  union { float f; unsigned int u; } c; c.f = f;
  unsigned int u = c.u;
  unsigned int r = (u + 0x7FFFu + ((u >> 16) & 1u)) >> 16;
  return (u16)r;
}
__device__ inline float bf2f(u16 h) {
  union { unsigned int u; float f; } c; c.u = ((unsigned int)h) << 16; return c.f;
}
__device__ inline float silu_fast(float v) {
  return v / (1.0f + __expf(-v));   // v_exp_f32 path; bf16 output absorbs error
}

// async 16B global->LDS DMA (m97: width=16 => global_load_lds_dwordx4)
__device__ inline void g2lds16(const u16* g, u16* l) {
  __builtin_amdgcn_global_load_lds(
      (const __attribute__((address_space(1))) void*)g,
      (__attribute__((address_space(3))) void*)l, 16, 0, 0);
}

// ---------------- LayerNorm: one block (256 thr) per row of H=1024 -----------
__global__ __launch_bounds__(256) void ln_kernel(const float* __restrict__ x,
                                                 const float* __restrict__ lw,
                                                 const float* __restrict__ lb,
                                                 u16* __restrict__ xn) {
  int row = blockIdx.x;
  int t = threadIdx.x;
  const float4* xr = (const float4*)(x + (size_t)row * H_);
  float4 v = xr[t];
  float s = v.x + v.y + v.z + v.w;
  float ss = v.x * v.x + v.y * v.y + v.z * v.z + v.w * v.w;
  for (int off = 1; off < 64; off <<= 1) {
    s += __shfl_xor(s, off);
    ss += __shfl_xor(ss, off);
  }
  __shared__ float red[8];
  int w = t >> 6, l = t & 63;
  if (l == 0) { red[w] = s; red[4 + w] = ss; }
  __syncthreads();
  s = red[0] + red[1] + red[2] + red[3];
  ss = red[4] + red[5] + red[6] + red[7];
  float mu = s * (1.0f / H_);
  float var = ss * (1.0f / H_) - mu * mu;
  float inv = rsqrtf(var + 1e-5f);
  int i = t * 4;
  ushort4 o;
  o.x = f2bf((v.x - mu) * inv * lw[i] + lb[i]);
  o.y = f2bf((v.y - mu) * inv * lw[i + 1] + lb[i + 1]);
  o.z = f2bf((v.z - mu) * inv * lw[i + 2] + lb[i + 2]);
  o.w = f2bf((v.w - mu) * inv * lw[i + 3] + lb[i + 3]);
  *(ushort4*)(xn + (size_t)row * H_ + i) = o;
}

// ---------------- f32 -> bf16 converter (n4 = count/4) -----------------------
__global__ void cvt_kernel(const float* __restrict__ in, u16* __restrict__ out, int n4) {
  int i = blockIdx.x * 256 + threadIdx.x;
  if (i < n4) {
    float4 v = ((const float4*)in)[i];
    ushort4 o;
    o.x = f2bf(v.x); o.y = f2bf(v.y); o.z = f2bf(v.z); o.w = f2bf(v.w);
    ((ushort4*)out)[i] = o;
  }
}

// ---------------- gamma/beta + RoPE -> q,k (bf16) ----------------------------
__global__ __launch_bounds__(256) void rope_kernel(const float* __restrict__ base,
                                                   const float* __restrict__ gamma,
                                                   const float* __restrict__ beta,
                                                   u16* __restrict__ q,
                                                   u16* __restrict__ k) {
  int row = blockIdx.x * 4 + (threadIdx.x >> 6);  // b*T + t
  int s = threadIdx.x & 63;
  int t = row & (T_ - 1);
  const float* bp = base + (size_t)row * S_;
  float b1 = bp[s], b2 = bp[s + 64];
  float q1 = b1 * gamma[s] + beta[s];
  float q2 = b2 * gamma[64 + s] + beta[64 + s];
  float k1 = b1 * gamma[128 + s] + beta[128 + s];
  float k2 = b2 * gamma[192 + s] + beta[192 + s];
  float invf = (float)pow(10000.0, (double)s * (1.0 / 64.0));
  float ph = (float)t * invf;
  float sn, cs;
  sincosf(ph, &sn, &cs);
  size_t o = (size_t)row * S_;
  q[o + s]      = f2bf(q1 * cs - q2 * sn);
  q[o + 64 + s] = f2bf(q2 * cs + q1 * sn);
  k[o + s]      = f2bf(k1 * cs - k2 * sn);
  k[o + 64 + s] = f2bf(k2 * cs + k1 * sn);
}

// ---------------- 128x128-tile bf16 MFMA GEMM, B^T form, BK=64 ---------------
// C[m][n] = sum_k A[m][k] * B[n][k];  A: M x K row-major, B: N x K row-major.
// grid: (N/128, M/128, Z). MODE selects fused epilogue. K % 64 == 0.
// Staging via global_load_lds width=16, lane-linear LDS dest (DMA req.).
// Tile row = 64 elems = 128 B. Bank swizzle: physical granule p of row r
// holds logical granule p ^ (r&7); staging thread t (instr c) covers row
// c*32+(t>>3), phys granule t&7, logical (t&7)^((t>>3)&7) -- global reads
// stay within the row's 128B (coalesced). Fragment reads address physical
// granule (j*4+quad)^(l16&7): each 8-lane group covers all 32 banks.
template <int MODE>
__global__ __launch_bounds__(256)
void gemm_bt(const u16* __restrict__ A, const u16* __restrict__ Bm,
             int K, long long sA, long long sB,
             void* __restrict__ o0, void* __restrict__ o1, void* __restrict__ o2,
             const void* __restrict__ c0, const void* __restrict__ c1) {
  // 32 KB LDS: A tile 128x64 (16 KB) + B tile 128x64 (16 KB).
  // v-path epilogue reuses first 16 KB as transpose buffer.
  __shared__ __attribute__((aligned(16))) u16 lds[16384];
  u16* lsA = lds;           // 128 rows x 64 cols
  u16* lsB = lds + 8192;    // 128 rows x 64 cols

  const int z = blockIdx.z;
  const u16* Ab = A + (long long)z * sA;
  const u16* Bb = Bm + (long long)z * sB;
  const int m0 = blockIdx.y * 128;
  const int n0 = blockIdx.x * 128;
  const int t = threadIdx.x;
  const int w = t >> 6, l = t & 63;
  const int quad = l >> 4, l16 = l & 15;
  const int wm = (w >> 1) * 64, wn = (w & 1) * 64;
  // staging: instr c covers rows [c*32, c*32+32); thread -> row c*32+(t>>3)
  const int srow = t >> 3;                       // 0..31
  const int gl = (t & 7) ^ ((t >> 3) & 7);       // logical source granule
  const int dst_off = srow * 64 + (t & 7) * 8;   // == t*8 elems (lane-linear)
  const int rsw = l16 & 7;                       // read-swizzle key per row

  f32x4 zero = {0.f, 0.f, 0.f, 0.f};
  f32x4 acc[4][4];
  for (int mi = 0; mi < 4; ++mi)
    for (int ni = 0; ni < 4; ++ni) acc[mi][ni] = zero;

  const u16* gA = Ab + ((size_t)(m0 + srow) * K + gl * 8);
  const u16* gB = Bb + ((size_t)(n0 + srow) * K + gl * 8);
  const size_t rK32 = (size_t)32 * K;

  for (int k0 = 0; k0 < K; k0 += 64) {
    __syncthreads();  // previous iteration's LDS reads complete
    g2lds16(gA + k0,            &lsA[dst_off]);
    g2lds16(gA + k0 +     rK32, &lsA[2048 + dst_off]);
    g2lds16(gA + k0 + 2 * rK32, &lsA[4096 + dst_off]);
    g2lds16(gA + k0 + 3 * rK32, &lsA[6144 + dst_off]);
    g2lds16(gB + k0,            &lsB[dst_off]);
    g2lds16(gB + k0 +     rK32, &lsB[2048 + dst_off]);
    g2lds16(gB + k0 + 2 * rK32, &lsB[4096 + dst_off]);
    g2lds16(gB + k0 + 3 * rK32, &lsB[6144 + dst_off]);
    __syncthreads();  // drain: 32 MFMA per drain now (was 16)
    for (int j = 0; j < 2; ++j) {
      int pg = ((j * 4 + quad) ^ rsw) * 8;   // physical granule offset (elems)
      bf16x8 af[4], bfr[4];
      for (int i = 0; i < 4; ++i) {
        af[i]  = *(const bf16x8*)&lsA[(wm + i * 16 + l16) * 64 + pg];
        bfr[i] = *(const bf16x8*)&lsB[(wn + i * 16 + l16) * 64 + pg];
      }
      for (int mi = 0; mi < 4; ++mi)
        for (int ni = 0; ni < 4; ++ni)
          acc[mi][ni] = __builtin_amdgcn_mfma_f32_16x16x32_bf16(af[mi], bfr[ni], acc[mi][ni], 0, 0, 0);
    }
  }

  // epilogue: C/D layout col = lane&15, row = quad*4 + reg   (m89/m91 verified)
  if constexpr (MODE == 0) {
    const float* uvb = (const float*)c0;
    if (n0 < E_) {
      // ---- u path: coalesced bf16 store, row-major m*E + n
      for (int mi = 0; mi < 4; ++mi)
        for (int ni = 0; ni < 4; ++ni) {
          int n = n0 + wn + ni * 16 + l16;
          float bias = uvb[n];
          for (int r = 0; r < 4; ++r) {
            int m = m0 + wm + mi * 16 + quad * 4 + r;
            ((u16*)o0)[(size_t)m * E_ + n] = f2bf(silu_fast(acc[mi][ni][r] + bias));
          }
        }
    } else if (n0 < 2 * E_) {
      // ---- v path: transpose through LDS, then coalesced rows of vt
      const int bb = m0 >> 9;          // batch
      const int tt0 = m0 & (T_ - 1);   // t offset within batch
      const int nv0 = n0 - E_;
      for (int h = 0; h < 2; ++h) {
        __syncthreads();               // LDS free (k-loop reads / prev half done)
        if ((w & 1) == h) {            // waves holding n in [n0+h*64, n0+h*64+64)
          for (int mi = 0; mi < 4; ++mi)
            for (int ni = 0; ni < 4; ++ni) {
              int nl = ni * 16 + l16;                 // 0..63 within half
              float bias = uvb[n0 + h * 64 + nl];
              for (int r = 0; r < 4; ++r) {
                int ml = wm + mi * 16 + quad * 4 + r; // 0..127
                u16 sv = f2bf(silu_fast(acc[mi][ni][r] + bias));
                int g = ml >> 3, o = ml & 7;
                int gs = g ^ (nl & 7);                // XOR swizzle, 8-elem granule
                lds[nl * 128 + gs * 8 + o] = sv;
              }
            }
        }
        __syncthreads();
        // readback: 256 threads; row = t>>2 (0..63), 4 x 16B chunks per thread
        int row = t >> 2;
        int q4 = t & 3;
        size_t gbase = ((size_t)bb * E_ + nv0 + h * 64 + row) * T_ + tt0;
        for (int gg = 0; gg < 4; ++gg) {
          int g = q4 * 4 + gg;
          int gsw = g ^ (row & 7);
          uint4 val = *(const uint4*)&lds[row * 128 + gsw * 8];
          *(uint4*)&(((u16*)o1)[gbase + g * 8]) = val;
        }
      }
    } else {
      // ---- base path: f32 store, m*S + n', coalesced 64B chunks
      for (int mi = 0; mi < 4; ++mi)
        for (int ni = 0; ni < 4; ++ni) {
          int n = n0 + wn + ni * 16 + l16;
          float bias = uvb[n];
          for (int r = 0; r < 4; ++r) {
            int m = m0 + wm + mi * 16 + quad * 4 + r;
            ((float*)o2)[(size_t)m * S_ + (n - 2 * E_)] = silu_fast(acc[mi][ni][r] + bias);
          }
        }
    }
  } else {
    for (int mi = 0; mi < 4; ++mi) {
      for (int ni = 0; ni < 4; ++ni) {
        int n = n0 + wn + ni * 16 + l16;
        for (int r = 0; r < 4; ++r) {
          int m = m0 + wm + mi * 16 + quad * 4 + r;
          float a = acc[mi][ni][r];
          if constexpr (MODE == 1) {
            // kernel = relu(qk/sqrt(S) + w[n-m+511])^2  -> bf16
            const float* wrel = (const float*)c0;
            float v = a * 0.08838834764831845f + wrel[n - m + 511];
            v = fmaxf(v, 0.0f);
            ((u16*)o0)[(size_t)z * (T_ * T_) + (size_t)m * T_ + n] = f2bf(v * v);
          } else if constexpr (MODE == 2) {
            // attn = (kernel @ v) * u  -> bf16, IN PLACE over u (o0 == c0)
            const u16* uu = (const u16*)c0;
            size_t gi = ((size_t)z * T_ + m) * E_ + n;
            float uv_ = bf2f(uu[gi]);  // read before write, same thread, same index
            ((u16*)o0)[gi] = f2bf(a * uv_);
          } else {
            // out = acc + o_b + shortcut  -> f32
            const float* ob = (const float*)c0;
            const float* xs = (const float*)c1;
            size_t gi = (size_t)m * H_ + n;
            ((float*)o0)[gi] = a + ob[n] + xs[gi];
          }
        }
      }
    }
  }
}

extern "C" void kernel_launch(void* const* d_in, const int* in_sizes, int n_in,
                              void* d_out, int out_size, void* d_ws, size_t ws_size,
                              hipStream_t stream) {
  const float* x     = (const float*)d_in[0];
  const float* ln_w  = (const float*)d_in[1];
  const float* ln_b  = (const float*)d_in[2];
  const float* uv_w  = (const float*)d_in[3];
  const float* uv_b  = (const float*)d_in[4];
  const float* gamma = (const float*)d_in[5];
  const float* beta  = (const float*)d_in[6];
  const float* wrel  = (const float*)d_in[7];
  const float* o_w   = (const float*)d_in[8];
  const float* o_b   = (const float*)d_in[9];

  // Workspace layout (total 189,005,824 B ≈ 180.3 MiB), with aliasing:
  //  - qb/kb/km live in the xn region (xn dead after GEMM0; stream-ordered)
  //  - attn is written in-place over u (element-wise read-then-write)
  char* ws = (char*)d_ws;
  u16*   xn   = (u16*)(ws);                 // 16384x1024 bf16  = 33554432 B
  u16*   qb   = (u16*)(ws);                 // 32x512x128 bf16  =  4194304 B (aliases xn)
  u16*   kb   = (u16*)(ws + 4194304);       // 32x512x128 bf16  =  4194304 B (aliases xn)
  u16*   km   = (u16*)(ws + 8388608);       // 32x512x512 bf16  = 16777216 B (aliases xn)
  u16*   uvwb = (u16*)(ws + 33554432);      // 4224x1024 bf16   =  8650752 B
  u16*   owb  = (u16*)(ws + 42205184);      // 1024x2048 bf16   =  4194304 B
  u16*   u    = (u16*)(ws + 46399488);      // 16384x2048 bf16  = 67108864 B (attn in-place)
  u16*   vt   = (u16*)(ws + 113508352);     // 32x2048x512 bf16 = 67108864 B
  float* base = (float*)(ws + 180617216);   // 16384x128 f32    =  8388608 B
  u16*   attn = u;

  // 1. LayerNorm -> bf16
  ln_kernel<<<16384, 256, 0, stream>>>(x, ln_w, ln_b, xn);
  // 2. weight conversions
  cvt_kernel<<<4224, 256, 0, stream>>>(uv_w, uvwb, 4224 * 1024 / 4);
  cvt_kernel<<<2048, 256, 0, stream>>>(o_w, owb, 1024 * 2048 / 4);
  // 3. uv GEMM: M=16384, N=4224, K=1024; epilogue silu + split u / v^T / base
  gemm_bt<0><<<dim3(33, 128, 1), 256, 0, stream>>>(xn, uvwb, 1024, 0, 0,
                                                   u, vt, base, uv_b, nullptr);
  // 4. gamma/beta + RoPE -> q,k  (xn now dead; qb/kb alias it)
  rope_kernel<<<4096, 256, 0, stream>>>(base, gamma, beta, qb, kb);
  // 5. qk per batch: M=N=512, K=128; epilogue bias + relu^2
  gemm_bt<1><<<dim3(4, 4, 32), 256, 0, stream>>>(qb, kb, 128, 65536, 65536,
                                                 km, nullptr, nullptr, wrel, nullptr);
  // 6. kernel @ v per batch: M=512, N=2048, K=512; epilogue * u (in place)
  gemm_bt<2><<<dim3(16, 4, 32), 256, 0, stream>>>(km, vt, 512, 262144, 1048576,
                                                  attn, nullptr, nullptr, u, nullptr);
  // 7. final: M=16384, N=1024, K=2048; epilogue + o_b + shortcut
  gemm_bt<3><<<dim3(8, 128, 1), 256, 0, stream>>>(attn, owb, 2048, 0, 0,
                                                  d_out, nullptr, nullptr, o_b, x);
}

// Round 7
// 552.468 us; speedup vs baseline: 1.2671x; 1.0503x over previous
//
#include <hip/hip_runtime.h>

typedef unsigned short u16;
typedef __bf16 bf16x8 __attribute__((ext_vector_type(8)));
typedef float f32x4 __attribute__((ext_vector_type(4)));

#define B_ 32
#define T_ 512
#define H_ 1024
#define E_ 2048
#define S_ 128

__device__ inline u16 f2bf(float f) {
  union { float f; unsigned int u; } c; c.f = f;
  unsigned int u = c.u;
  unsigned int r = (u + 0x7FFFu + ((u >> 16) & 1u)) >> 16;
  return (u16)r;
}
__device__ inline float bf2f(u16 h) {
  union { unsigned int u; float f; } c; c.u = ((unsigned int)h) << 16; return c.f;
}
__device__ inline float silu_fast(float v) {
  // v_exp_f32 + v_rcp_f32; bf16 output absorbs the ~1-ulp rcp error
  return v * __builtin_amdgcn_rcpf(1.0f + __expf(-v));
}

// async 16B global->LDS DMA (m97: width=16 => global_load_lds_dwordx4)
__device__ inline void g2lds16(const u16* g, u16* l) {
  __builtin_amdgcn_global_load_lds(
      (const __attribute__((address_space(1))) void*)g,
      (__attribute__((address_space(3))) void*)l, 16, 0, 0);
}

// ---------------- LayerNorm: one block (256 thr) per row of H=1024 -----------
__global__ __launch_bounds__(256) void ln_kernel(const float* __restrict__ x,
                                                 const float* __restrict__ lw,
                                                 const float* __restrict__ lb,
                                                 u16* __restrict__ xn) {
  int row = blockIdx.x;
  int t = threadIdx.x;
  const float4* xr = (const float4*)(x + (size_t)row * H_);
  float4 v = xr[t];
  float s = v.x + v.y + v.z + v.w;
  float ss = v.x * v.x + v.y * v.y + v.z * v.z + v.w * v.w;
  for (int off = 1; off < 64; off <<= 1) {
    s += __shfl_xor(s, off);
    ss += __shfl_xor(ss, off);
  }
  __shared__ float red[8];
  int w = t >> 6, l = t & 63;
  if (l == 0) { red[w] = s; red[4 + w] = ss; }
  __syncthreads();
  s = red[0] + red[1] + red[2] + red[3];
  ss = red[4] + red[5] + red[6] + red[7];
  float mu = s * (1.0f / H_);
  float var = ss * (1.0f / H_) - mu * mu;
  float inv = rsqrtf(var + 1e-5f);
  int i = t * 4;
  ushort4 o;
  o.x = f2bf((v.x - mu) * inv * lw[i] + lb[i]);
  o.y = f2bf((v.y - mu) * inv * lw[i + 1] + lb[i + 1]);
  o.z = f2bf((v.z - mu) * inv * lw[i + 2] + lb[i + 2]);
  o.w = f2bf((v.w - mu) * inv * lw[i + 3] + lb[i + 3]);
  *(ushort4*)(xn + (size_t)row * H_ + i) = o;
}

// ---------------- f32 -> bf16 converter (n4 = count/4) -----------------------
__global__ void cvt_kernel(const float* __restrict__ in, u16* __restrict__ out, int n4) {
  int i = blockIdx.x * 256 + threadIdx.x;
  if (i < n4) {
    float4 v = ((const float4*)in)[i];
    ushort4 o;
    o.x = f2bf(v.x); o.y = f2bf(v.y); o.z = f2bf(v.z); o.w = f2bf(v.w);
    ((ushort4*)out)[i] = o;
  }
}

// ---------------- gamma/beta + RoPE -> q,k (bf16) ----------------------------
__global__ __launch_bounds__(256) void rope_kernel(const float* __restrict__ base,
                                                   const float* __restrict__ gamma,
                                                   const float* __restrict__ beta,
                                                   u16* __restrict__ q,
                                                   u16* __restrict__ k) {
  int row = blockIdx.x * 4 + (threadIdx.x >> 6);  // b*T + t
  int s = threadIdx.x & 63;
  int t = row & (T_ - 1);
  const float* bp = base + (size_t)row * S_;
  float b1 = bp[s], b2 = bp[s + 64];
  float q1 = b1 * gamma[s] + beta[s];
  float q2 = b2 * gamma[64 + s] + beta[64 + s];
  float k1 = b1 * gamma[128 + s] + beta[128 + s];
  float k2 = b2 * gamma[192 + s] + beta[192 + s];
  float invf = (float)pow(10000.0, (double)s * (1.0 / 64.0));
  float ph = (float)t * invf;
  float sn, cs;
  sincosf(ph, &sn, &cs);
  size_t o = (size_t)row * S_;
  q[o + s]      = f2bf(q1 * cs - q2 * sn);
  q[o + 64 + s] = f2bf(q2 * cs + q1 * sn);
  k[o + s]      = f2bf(k1 * cs - k2 * sn);
  k[o + 64 + s] = f2bf(k2 * cs + k1 * sn);
}

// ---------------- 128x128-tile bf16 MFMA GEMM, B^T form, BK=128 --------------
// C[m][n] = sum_k A[m][k] * B[n][k];  A: M x K row-major, B: N x K row-major.
// grid: (N/128, M/128, Z). MODE selects fused epilogue. K % 128 == 0.
// Staging via global_load_lds width=16, lane-linear LDS dest (DMA req.).
// Tile row = 128 elems = 256 B = 16 granules of 16 B. Bank swizzle: physical
// granule p of row r holds logical granule p ^ (r&7) (low-3-bit XOR).
// Staging thread t (instr c): row c*16+(t>>4), phys granule t&15, logical
// (t&15)^((t>>4)&7) -- global reads stay inside the row's 256 B (coalesced).
// Fragment reads: phys granule (j*4+quad)^(l16&7): each 8-lane group covers
// all 32 banks exactly once. 64 MFMA per barrier-drain (2x round 6).
template <int MODE>
__global__ __launch_bounds__(256)
void gemm_bt(const u16* __restrict__ A, const u16* __restrict__ Bm,
             int K, long long sA, long long sB,
             void* __restrict__ o0, void* __restrict__ o1, void* __restrict__ o2,
             const void* __restrict__ c0, const void* __restrict__ c1) {
  // 64 KB LDS: A tile 128x128 (32 KB) + B tile 128x128 (32 KB).
  // v-path epilogue reuses first 16 KB as transpose buffer.
  __shared__ __attribute__((aligned(16))) u16 lds[32768];
  u16* lsA = lds;           // 128 rows x 128 cols
  u16* lsB = lds + 16384;   // 128 rows x 128 cols

  const int z = blockIdx.z;
  const u16* Ab = A + (long long)z * sA;
  const u16* Bb = Bm + (long long)z * sB;
  const int m0 = blockIdx.y * 128;
  const int n0 = blockIdx.x * 128;
  const int t = threadIdx.x;
  const int w = t >> 6, l = t & 63;
  const int quad = l >> 4, l16 = l & 15;
  const int wm = (w >> 1) * 64, wn = (w & 1) * 64;
  // staging: instr c covers rows [c*16, c*16+16); thread -> row c*16+(t>>4)
  const int srow = t >> 4;                       // 0..15
  const int gl = (t & 15) ^ ((t >> 4) & 7);      // logical source granule
  const int dst_off = t * 8;                     // elems; lane-linear (DMA req.)
  const int rsw = l16 & 7;                       // read-swizzle key per row

  f32x4 zero = {0.f, 0.f, 0.f, 0.f};
  f32x4 acc[4][4];
  for (int mi = 0; mi < 4; ++mi)
    for (int ni = 0; ni < 4; ++ni) acc[mi][ni] = zero;

  const u16* gA = Ab + ((size_t)(m0 + srow) * K + gl * 8);
  const u16* gB = Bb + ((size_t)(n0 + srow) * K + gl * 8);
  const size_t rK16 = (size_t)16 * K;

  for (int k0 = 0; k0 < K; k0 += 128) {
    __syncthreads();  // previous iteration's LDS reads complete
#pragma unroll
    for (int c = 0; c < 8; ++c)
      g2lds16(gA + k0 + c * rK16, &lsA[c * 2048 + dst_off]);
#pragma unroll
    for (int c = 0; c < 8; ++c)
      g2lds16(gB + k0 + c * rK16, &lsB[c * 2048 + dst_off]);
    __syncthreads();  // drain: 64 MFMA per drain now (was 32)
#pragma unroll
    for (int j = 0; j < 4; ++j) {
      int pg = ((j * 4 + quad) ^ rsw) * 8;   // physical granule offset (elems)
      bf16x8 af[4], bfr[4];
      for (int i = 0; i < 4; ++i) {
        af[i]  = *(const bf16x8*)&lsA[(wm + i * 16 + l16) * 128 + pg];
        bfr[i] = *(const bf16x8*)&lsB[(wn + i * 16 + l16) * 128 + pg];
      }
      for (int mi = 0; mi < 4; ++mi)
        for (int ni = 0; ni < 4; ++ni)
          acc[mi][ni] = __builtin_amdgcn_mfma_f32_16x16x32_bf16(af[mi], bfr[ni], acc[mi][ni], 0, 0, 0);
    }
  }

  // epilogue: C/D layout col = lane&15, row = quad*4 + reg   (m89/m91 verified)
  if constexpr (MODE == 0) {
    const float* uvb = (const float*)c0;
    if (n0 < E_) {
      // ---- u path: coalesced bf16 store, row-major m*E + n
      for (int mi = 0; mi < 4; ++mi)
        for (int ni = 0; ni < 4; ++ni) {
          int n = n0 + wn + ni * 16 + l16;
          float bias = uvb[n];
          for (int r = 0; r < 4; ++r) {
            int m = m0 + wm + mi * 16 + quad * 4 + r;
            ((u16*)o0)[(size_t)m * E_ + n] = f2bf(silu_fast(acc[mi][ni][r] + bias));
          }
        }
    } else if (n0 < 2 * E_) {
      // ---- v path: transpose through LDS, then coalesced rows of vt
      const int bb = m0 >> 9;          // batch
      const int tt0 = m0 & (T_ - 1);   // t offset within batch
      const int nv0 = n0 - E_;
      for (int h = 0; h < 2; ++h) {
        __syncthreads();               // LDS free (k-loop reads / prev half done)
        if ((w & 1) == h) {            // waves holding n in [n0+h*64, n0+h*64+64)
          for (int mi = 0; mi < 4; ++mi)
            for (int ni = 0; ni < 4; ++ni) {
              int nl = ni * 16 + l16;                 // 0..63 within half
              float bias = uvb[n0 + h * 64 + nl];
              for (int r = 0; r < 4; ++r) {
                int ml = wm + mi * 16 + quad * 4 + r; // 0..127
                u16 sv = f2bf(silu_fast(acc[mi][ni][r] + bias));
                int g = ml >> 3, o = ml & 7;
                int gs = g ^ (nl & 7);                // XOR swizzle, 8-elem granule
                lds[nl * 128 + gs * 8 + o] = sv;
              }
            }
        }
        __syncthreads();
        // readback: 256 threads; row = t>>2 (0..63), 4 x 16B chunks per thread
        int row = t >> 2;
        int q4 = t & 3;
        size_t gbase = ((size_t)bb * E_ + nv0 + h * 64 + row) * T_ + tt0;
        for (int gg = 0; gg < 4; ++gg) {
          int g = q4 * 4 + gg;
          int gsw = g ^ (row & 7);
          uint4 val = *(const uint4*)&lds[row * 128 + gsw * 8];
          *(uint4*)&(((u16*)o1)[gbase + g * 8]) = val;
        }
      }
    } else {
      // ---- base path: f32 store, m*S + n', coalesced 64B chunks
      for (int mi = 0; mi < 4; ++mi)
        for (int ni = 0; ni < 4; ++ni) {
          int n = n0 + wn + ni * 16 + l16;
          float bias = uvb[n];
          for (int r = 0; r < 4; ++r) {
            int m = m0 + wm + mi * 16 + quad * 4 + r;
            ((float*)o2)[(size_t)m * S_ + (n - 2 * E_)] = silu_fast(acc[mi][ni][r] + bias);
          }
        }
    }
  } else {
    for (int mi = 0; mi < 4; ++mi) {
      for (int ni = 0; ni < 4; ++ni) {
        int n = n0 + wn + ni * 16 + l16;
        for (int r = 0; r < 4; ++r) {
          int m = m0 + wm + mi * 16 + quad * 4 + r;
          float a = acc[mi][ni][r];
          if constexpr (MODE == 1) {
            // kernel = relu(qk/sqrt(S) + w[n-m+511])^2  -> bf16
            const float* wrel = (const float*)c0;
            float v = a * 0.08838834764831845f + wrel[n - m + 511];
            v = fmaxf(v, 0.0f);
            ((u16*)o0)[(size_t)z * (T_ * T_) + (size_t)m * T_ + n] = f2bf(v * v);
          } else if constexpr (MODE == 2) {
            // attn = (kernel @ v) * u  -> bf16, IN PLACE over u (o0 == c0)
            const u16* uu = (const u16*)c0;
            size_t gi = ((size_t)z * T_ + m) * E_ + n;
            float uv_ = bf2f(uu[gi]);  // read before write, same thread, same index
            ((u16*)o0)[gi] = f2bf(a * uv_);
          } else {
            // out = acc + o_b + shortcut  -> f32
            const float* ob = (const float*)c0;
            const float* xs = (const float*)c1;
            size_t gi = (size_t)m * H_ + n;
            ((float*)o0)[gi] = a + ob[n] + xs[gi];
          }
        }
      }
    }
  }
}

extern "C" void kernel_launch(void* const* d_in, const int* in_sizes, int n_in,
                              void* d_out, int out_size, void* d_ws, size_t ws_size,
                              hipStream_t stream) {
  const float* x     = (const float*)d_in[0];
  const float* ln_w  = (const float*)d_in[1];
  const float* ln_b  = (const float*)d_in[2];
  const float* uv_w  = (const float*)d_in[3];
  const float* uv_b  = (const float*)d_in[4];
  const float* gamma = (const float*)d_in[5];
  const float* beta  = (const float*)d_in[6];
  const float* wrel  = (const float*)d_in[7];
  const float* o_w   = (const float*)d_in[8];
  const float* o_b   = (const float*)d_in[9];

  // Workspace layout (total 189,005,824 B ≈ 180.3 MiB), with aliasing:
  //  - qb/kb/km live in the xn region (xn dead after GEMM0; stream-ordered)
  //  - attn is written in-place over u (element-wise read-then-write)
  char* ws = (char*)d_ws;
  u16*   xn   = (u16*)(ws);                 // 16384x1024 bf16  = 33554432 B
  u16*   qb   = (u16*)(ws);                 // 32x512x128 bf16  =  4194304 B (aliases xn)
  u16*   kb   = (u16*)(ws + 4194304);       // 32x512x128 bf16  =  4194304 B (aliases xn)
  u16*   km   = (u16*)(ws + 8388608);       // 32x512x512 bf16  = 16777216 B (aliases xn)
  u16*   uvwb = (u16*)(ws + 33554432);      // 4224x1024 bf16   =  8650752 B
  u16*   owb  = (u16*)(ws + 42205184);      // 1024x2048 bf16   =  4194304 B
  u16*   u    = (u16*)(ws + 46399488);      // 16384x2048 bf16  = 67108864 B (attn in-place)
  u16*   vt   = (u16*)(ws + 113508352);     // 32x2048x512 bf16 = 67108864 B
  float* base = (float*)(ws + 180617216);   // 16384x128 f32    =  8388608 B
  u16*   attn = u;

  // 1. LayerNorm -> bf16
  ln_kernel<<<16384, 256, 0, stream>>>(x, ln_w, ln_b, xn);
  // 2. weight conversions
  cvt_kernel<<<4224, 256, 0, stream>>>(uv_w, uvwb, 4224 * 1024 / 4);
  cvt_kernel<<<2048, 256, 0, stream>>>(o_w, owb, 1024 * 2048 / 4);
  // 3. uv GEMM: M=16384, N=4224, K=1024; epilogue silu + split u / v^T / base
  gemm_bt<0><<<dim3(33, 128, 1), 256, 0, stream>>>(xn, uvwb, 1024, 0, 0,
                                                   u, vt, base, uv_b, nullptr);
  // 4. gamma/beta + RoPE -> q,k  (xn now dead; qb/kb alias it)
  rope_kernel<<<4096, 256, 0, stream>>>(base, gamma, beta, qb, kb);
  // 5. qk per batch: M=N=512, K=128; epilogue bias + relu^2
  gemm_bt<1><<<dim3(4, 4, 32), 256, 0, stream>>>(qb, kb, 128, 65536, 65536,
                                                 km, nullptr, nullptr, wrel, nullptr);
  // 6. kernel @ v per batch: M=512, N=2048, K=512; epilogue * u (in place)
  gemm_bt<2><<<dim3(16, 4, 32), 256, 0, stream>>>(km, vt, 512, 262144, 1048576,
                                                  attn, nullptr, nullptr, u, nullptr);
  // 7. final: M=16384, N=1024, K=2048; epilogue + o_b + shortcut
  gemm_bt<3><<<dim3(8, 128, 1), 256, 0, stream>>>(attn, owb, 2048, 0, 0,
                                                  d_out, nullptr, nullptr, o_b, x);
}